// Round 1
// baseline (276.017 us; speedup 1.0000x reference)
//
#include <hip/hip_runtime.h>
#include <hip/hip_bf16.h>

// Problem constants (from reference): B=16, P=64, De=512, F=128, H=8, hs=64, d_model=512.
// Math restructure:
//   K0 = pe @ Wk[:512], V0 = pe @ Wv[:512], Q = pe @ Wq            (GEMMs, [1024,512])
//   scores[b,q,h,kk] = (q_h . K0[b,kk,h]) + sum_f relf[b,q,kk,f]*u[h,f],
//       u[h,f] = sum_d q[h*64+d] * Wk[(512+f)*512 + h*64+d]
//   attn = softmax_kk(scores/8)
//   AO[b,q,h,d] = sum_kk attn*V0[b,kk,h*64+d] + sum_f w[h,f]*Wv[(512+f)*512+h*64+d],
//       w[h,f] = sum_kk attn[kk]*relf[b,q,kk,f]
//   out = AO @ Wo                                                    (GEMM)

#define GT 64
#define GK 16

__global__ __launch_bounds__(256) void gemm64(const float* __restrict__ A,
                                              const float* __restrict__ B,
                                              float* __restrict__ C,
                                              int K, int lda, int ldb, int ldc) {
  // C[m0:m0+64, n0:n0+64] = A[m0:, :K] @ B[:K, n0:]
  __shared__ float As[GK][GT + 4];  // As[k][m], stride 68 keeps 16B alignment (272B rows)
  __shared__ float Bs[GK][GT + 4];  // Bs[k][n]
  const int m0 = blockIdx.x * GT, n0 = blockIdx.y * GT;
  const int tid = threadIdx.x;
  const int tx = tid & 15, ty = tid >> 4;
  float acc[4][4] = {};
  for (int k0 = 0; k0 < K; k0 += GK) {
    {
      // A tile 64x16: thread -> row r, 4 cols
      int r = tid >> 2, cq = (tid & 3) * 4;
      float4 ga = *(const float4*)(A + (size_t)(m0 + r) * lda + k0 + cq);
      As[cq + 0][r] = ga.x; As[cq + 1][r] = ga.y; As[cq + 2][r] = ga.z; As[cq + 3][r] = ga.w;
      // B tile 16x64: thread -> row rr, 4 cols
      int rr = tid >> 4, cc = (tid & 15) * 4;
      float4 gb = *(const float4*)(B + (size_t)(k0 + rr) * ldb + n0 + cc);
      Bs[rr][cc + 0] = gb.x; Bs[rr][cc + 1] = gb.y; Bs[rr][cc + 2] = gb.z; Bs[rr][cc + 3] = gb.w;
    }
    __syncthreads();
#pragma unroll
    for (int k = 0; k < GK; ++k) {
      float4 a = *(const float4*)&As[k][ty * 4];
      float4 b = *(const float4*)&Bs[k][tx * 4];
      float av[4] = {a.x, a.y, a.z, a.w};
      float bv[4] = {b.x, b.y, b.z, b.w};
#pragma unroll
      for (int i = 0; i < 4; ++i)
#pragma unroll
        for (int j = 0; j < 4; ++j) acc[i][j] += av[i] * bv[j];
    }
    __syncthreads();
  }
#pragma unroll
  for (int i = 0; i < 4; ++i) {
    float4 o = {acc[i][0], acc[i][1], acc[i][2], acc[i][3]};
    *(float4*)(C + (size_t)(m0 + ty * 4 + i) * ldc + n0 + tx * 4) = o;
  }
}

__global__ __launch_bounds__(256) void attn_fused(const float* __restrict__ Q,
                                                  const float* __restrict__ K0,
                                                  const float* __restrict__ V0,
                                                  const float* __restrict__ relf,
                                                  const float* __restrict__ Wk,
                                                  const float* __restrict__ Wv,
                                                  float* __restrict__ AO) {
  const int bq = blockIdx.x;      // b*64 + q
  const int b = bq >> 6;
  const int tid = threadIdx.x;
  const int wave = tid >> 6, lane = tid & 63;

  __shared__ float relf_s[64][129];  // +1 pad: (kk+f)%32 banks -> 2-way (free) both sweeps
  __shared__ float q_s[512];
  __shared__ float u_s[8][128];
  __shared__ float attn_s[4][64];
  __shared__ float w_s[4][128];

  // stage q row
  const float* qrow = Q + (size_t)bq * 512;
  q_s[tid] = qrow[tid];
  q_s[tid + 256] = qrow[tid + 256];

  // stage relf[b,q] : 64x128 f32, coalesced float4 reads
  const float* rf = relf + (size_t)bq * 8192;
#pragma unroll
  for (int it = 0; it < 8; ++it) {
    int idx = (it * 256 + tid) * 4;
    float4 g = *(const float4*)(rf + idx);
    int kk = idx >> 7, f = idx & 127;
    relf_s[kk][f + 0] = g.x; relf_s[kk][f + 1] = g.y;
    relf_s[kk][f + 2] = g.z; relf_s[kk][f + 3] = g.w;
  }
  __syncthreads();

  // u[h][f] = q_h . Wk2[f, h-block] ; 1024 dots of length 64, 4 per thread
  const float* Wk2 = Wk + 512 * 512;
#pragma unroll
  for (int j = 0; j < 4; ++j) {
    int idx = j * 256 + tid;  // h*128 + f
    int h = idx >> 7, f = idx & 127;
    const float4* wrow = (const float4*)(Wk2 + (size_t)f * 512 + h * 64);
    float acc = 0.f;
#pragma unroll
    for (int d4 = 0; d4 < 16; ++d4) {
      float4 wv = wrow[d4];
      int d = h * 64 + d4 * 4;
      acc += q_s[d] * wv.x + q_s[d + 1] * wv.y + q_s[d + 2] * wv.z + q_s[d + 3] * wv.w;
    }
    u_s[h][f] = acc;
  }
  __syncthreads();

  const float* Wv2 = Wv + 512 * 512;
  const float scale = 0.125f;

  // each wave handles heads {wave, wave+4}; lane roles: kk for scores, f for w, d for out
  for (int h = wave; h < 8; h += 4) {
    // scores: lane = kk
    const float* k0row = K0 + ((size_t)b * 64 + lane) * 512 + h * 64;
    float s = 0.f;
#pragma unroll
    for (int d4 = 0; d4 < 64; d4 += 4) {
      float4 kv = *(const float4*)(k0row + d4);
      int d = h * 64 + d4;
      s += q_s[d] * kv.x + q_s[d + 1] * kv.y + q_s[d + 2] * kv.z + q_s[d + 3] * kv.w;
    }
#pragma unroll 8
    for (int f = 0; f < 128; ++f) s += u_s[h][f] * relf_s[lane][f];
    s *= scale;
    // in-wave softmax over 64 kk
    float m = s;
#pragma unroll
    for (int off = 32; off; off >>= 1) m = fmaxf(m, __shfl_xor(m, off));
    float p = __expf(s - m);
    float sum = p;
#pragma unroll
    for (int off = 32; off; off >>= 1) sum += __shfl_xor(sum, off);
    attn_s[wave][lane] = p / sum;
    __syncthreads();

    // w[f] = attn . relf[:,f] ; lane covers f = lane, lane+64
    float w0 = 0.f, w1 = 0.f;
#pragma unroll 8
    for (int kk = 0; kk < 64; ++kk) {
      float a = attn_s[wave][kk];
      w0 += a * relf_s[kk][lane];
      w1 += a * relf_s[kk][lane + 64];
    }
    w_s[wave][lane] = w0;
    w_s[wave][lane + 64] = w1;
    __syncthreads();

    // out: lane = d
    float o = 0.f;
    const float* v0col = V0 + (size_t)b * 64 * 512 + h * 64 + lane;
#pragma unroll 8
    for (int kk = 0; kk < 64; ++kk) o += attn_s[wave][kk] * v0col[(size_t)kk * 512];
    const float* wvcol = Wv2 + h * 64 + lane;
#pragma unroll 8
    for (int f = 0; f < 128; ++f) o += w_s[wave][f] * wvcol[(size_t)f * 512];
    AO[(size_t)bq * 512 + h * 64 + lane] = o;
  }
}

extern "C" void kernel_launch(void* const* d_in, const int* in_sizes, int n_in,
                              void* d_out, int out_size, void* d_ws, size_t ws_size,
                              hipStream_t stream) {
  const float* pe   = (const float*)d_in[0];  // [16,64,512]
  const float* relf = (const float*)d_in[1];  // [16,64,64,128]
  // d_in[2] = mask (all true, unused by reference)
  const float* Wq = (const float*)d_in[3];  // [512,512]
  const float* Wk = (const float*)d_in[4];  // [640,512]
  const float* Wv = (const float*)d_in[5];  // [640,512]
  const float* Wo = (const float*)d_in[6];  // [512,512]
  float* out = (float*)d_out;               // [16,64,512]

  float* ws = (float*)d_ws;
  float* Qb = ws;                 // [1024,512]
  float* K0 = ws + 524288;        // [1024,512]
  float* V0 = ws + 2 * 524288;    // [1024,512]
  float* AO = ws + 3 * 524288;    // [1024,512]

  dim3 gg(16, 8);
  gemm64<<<gg, 256, 0, stream>>>(pe, Wq, Qb, 512, 512, 512, 512);
  gemm64<<<gg, 256, 0, stream>>>(pe, Wk, K0, 512, 512, 512, 512);
  gemm64<<<gg, 256, 0, stream>>>(pe, Wv, V0, 512, 512, 512, 512);
  attn_fused<<<1024, 256, 0, stream>>>(Qb, K0, V0, relf, Wk, Wv, AO);
  gemm64<<<gg, 256, 0, stream>>>(AO, Wo, out, 512, 512, 512, 512);
}

// Round 2
// 195.656 us; speedup vs baseline: 1.4107x; 1.4107x over previous
//
#include <hip/hip_runtime.h>
#include <hip/hip_bf16.h>

// B=16, P=64, De=512, F=128, H=8, hs=64, d_model=512.
// Restructure:
//   QKV = pe @ [Wq | Wk[:512] | Wv[:512]]   (one MFMA bf16 GEMM, [1024,1536])
//   u[b,q,h,f]   = q_h . Wk2[f,h-block]                  (in attn kernel)
//   scores[kk]   = q_h.K0[kk,h] + relf[b,q,kk,:].u_h     -> softmax
//   AO[h,d]      = attn.V0[:,h,d] + (attn@relf)[f].Wv2[f,h,d]
//   out = AO @ Wo                            (MFMA bf16 GEMM)

typedef __attribute__((ext_vector_type(8))) short short8;
typedef __attribute__((ext_vector_type(4))) short short4v;
typedef __attribute__((ext_vector_type(4))) float f32x4;

static __device__ __forceinline__ short f2bf(float x) {
  __hip_bfloat16 h = __float2bfloat16(x);
  union { __hip_bfloat16 h; short s; } u;
  u.h = h;
  return u.s;
}
static __device__ __forceinline__ float bf2f(short s) {
  union { unsigned int u; float f; } c;
  c.u = ((unsigned int)(unsigned short)s) << 16;
  return c.f;
}

// ---- prep: cast pe (f32 [1024,512]) -> bf16, row-major ----
__global__ __launch_bounds__(256) void cast_pe(const float* __restrict__ pe,
                                               short* __restrict__ out) {
  int i = (blockIdx.x * 256 + threadIdx.x) * 4;
  float4 v = *(const float4*)(pe + i);
  short4v o = {f2bf(v.x), f2bf(v.y), f2bf(v.z), f2bf(v.w)};
  *(short4v*)(out + i) = o;
}

// ---- prep: transpose-cast weights. Output Bt[n][k] = W[k][n] as bf16.
// n in [0,1536): [Wq|Wk0|Wv0] -> BtQKV ; n in [1536,2048): Wo -> BtO.
__global__ __launch_bounds__(256) void tcast(const float* __restrict__ Wq,
                                             const float* __restrict__ Wk,
                                             const float* __restrict__ Wv,
                                             const float* __restrict__ Wo,
                                             short* __restrict__ BtQKV,
                                             short* __restrict__ BtO) {
  __shared__ float t[32][33];
  const int n0 = blockIdx.x * 32;  // 0..2047, never crosses a 512 boundary
  const int k0 = blockIdx.y * 32;  // 0..511
  const int tx = threadIdx.x & 31, ty = threadIdx.x >> 5;
  const int sid = n0 >> 9;
  const float* src = (sid == 0) ? Wq : (sid == 1) ? Wk : (sid == 2) ? Wv : Wo;
  const int nc0 = n0 & 511;
#pragma unroll
  for (int r = 0; r < 4; ++r) {
    int kl = ty + r * 8;
    t[kl][tx] = src[(size_t)(k0 + kl) * 512 + nc0 + tx];
  }
  __syncthreads();
#pragma unroll
  for (int r = 0; r < 4; ++r) {
    int nl = ty + r * 8;
    short bv = f2bf(t[tx][nl]);
    int ng = n0 + nl;
    if (ng < 1536) BtQKV[(size_t)ng * 512 + k0 + tx] = bv;
    else           BtO[(size_t)(ng - 1536) * 512 + k0 + tx] = bv;
  }
}

// ---- MFMA bf16 GEMM: C[M,N] = A[M,K] @ Bt[N,K]^T, K=512.
// 64x64 tile / block, 4 waves each 32x32 (2x2 of 16x16x32 frags),
// fragments loaded straight from global (operands are L2-resident).
template <int OUTBF>
__global__ __launch_bounds__(256) void gemm_mfma(const short* __restrict__ A,
                                                 const short* __restrict__ Bt,
                                                 float* __restrict__ Cf,
                                                 short* __restrict__ Cb,
                                                 int K, int ldc) {
  const int wave = threadIdx.x >> 6, lane = threadIdx.x & 63;
  const int wr = wave >> 1, wc = wave & 1;
  const int r = lane & 15, g = lane >> 4;
  const int row0 = blockIdx.x * 64 + wr * 32;
  const int col0 = blockIdx.y * 64 + wc * 32;
  const short8* a0p = (const short8*)(A + (size_t)(row0 + r) * K + g * 8);
  const short8* a1p = (const short8*)(A + (size_t)(row0 + 16 + r) * K + g * 8);
  const short8* b0p = (const short8*)(Bt + (size_t)(col0 + r) * K + g * 8);
  const short8* b1p = (const short8*)(Bt + (size_t)(col0 + 16 + r) * K + g * 8);
  f32x4 acc00 = {}, acc01 = {}, acc10 = {}, acc11 = {};
  const int steps = K >> 5;
#pragma unroll 4
  for (int t = 0; t < steps; ++t) {
    short8 a0 = a0p[t * 4], a1 = a1p[t * 4];
    short8 b0 = b0p[t * 4], b1 = b1p[t * 4];
    acc00 = __builtin_amdgcn_mfma_f32_16x16x32_bf16(a0, b0, acc00, 0, 0, 0);
    acc01 = __builtin_amdgcn_mfma_f32_16x16x32_bf16(a0, b1, acc01, 0, 0, 0);
    acc10 = __builtin_amdgcn_mfma_f32_16x16x32_bf16(a1, b0, acc10, 0, 0, 0);
    acc11 = __builtin_amdgcn_mfma_f32_16x16x32_bf16(a1, b1, acc11, 0, 0, 0);
  }
  const int crow = (lane >> 4) * 4, ccol = lane & 15;
#pragma unroll
  for (int i = 0; i < 2; ++i)
#pragma unroll
    for (int j = 0; j < 2; ++j) {
      f32x4 a = (i == 0) ? (j == 0 ? acc00 : acc01) : (j == 0 ? acc10 : acc11);
#pragma unroll
      for (int rg = 0; rg < 4; ++rg) {
        size_t row = row0 + i * 16 + crow + rg;
        size_t col = col0 + j * 16 + ccol;
        if (OUTBF) Cb[row * ldc + col] = f2bf(a[rg]);
        else       Cf[row * ldc + col] = a[rg];
      }
    }
}

// ---- fused attention: one block per (b,q), 8 waves = 1 head each ----
__global__ __launch_bounds__(512) void attn_fused(const short* __restrict__ QKV,  // [1024][1536] bf16: Q|K0|V0
                                                  const float* __restrict__ relf,
                                                  const float* __restrict__ Wk,
                                                  const float* __restrict__ Wv,
                                                  short* __restrict__ AO) {
  const int bq = blockIdx.x, b = bq >> 6;
  const int tid = threadIdx.x;
  const int h = tid >> 6, lane = tid & 63;

  __shared__ float relf_s[64][129];  // stride 129: conflict-free row & col sweeps
  __shared__ float q_s[512];
  __shared__ float u_s[8][128];
  __shared__ float attn_s[8][64];
  __shared__ float w_s[8][128];

  // stage q (bf16 -> f32)
  q_s[tid] = bf2f(QKV[(size_t)bq * 1536 + tid]);

  // stage relf[b,q]: 64x128 f32, coalesced float4
  const float* rf = relf + (size_t)bq * 8192;
#pragma unroll
  for (int it = 0; it < 4; ++it) {
    int idx = (it * 512 + tid) * 4;
    float4 gv = *(const float4*)(rf + idx);
    int kk = idx >> 7, f = idx & 127;
    relf_s[kk][f + 0] = gv.x; relf_s[kk][f + 1] = gv.y;
    relf_s[kk][f + 2] = gv.z; relf_s[kk][f + 3] = gv.w;
  }
  __syncthreads();  // the only block-wide barrier

  // u[h][f] for f = lane, lane+64 : dot(q_h, Wk2[f, h-block])
  const float* Wk2 = Wk + 512 * 512;
  {
    const float4* w0p = (const float4*)(Wk2 + (size_t)lane * 512 + h * 64);
    const float4* w1p = (const float4*)(Wk2 + (size_t)(lane + 64) * 512 + h * 64);
    float u0 = 0.f, u1 = 0.f;
#pragma unroll
    for (int d4 = 0; d4 < 16; ++d4) {
      float4 wa = w0p[d4], wb = w1p[d4];
      float q0 = q_s[h * 64 + d4 * 4 + 0], q1 = q_s[h * 64 + d4 * 4 + 1];
      float q2 = q_s[h * 64 + d4 * 4 + 2], q3 = q_s[h * 64 + d4 * 4 + 3];
      u0 += q0 * wa.x + q1 * wa.y + q2 * wa.z + q3 * wa.w;
      u1 += q0 * wb.x + q1 * wb.y + q2 * wb.z + q3 * wb.w;
    }
    u_s[h][lane] = u0;
    u_s[h][lane + 64] = u1;
  }

  // scores: lane = kk
  float s = 0.f;
  {
    const short8* k0p = (const short8*)(QKV + (size_t)(b * 64 + lane) * 1536 + 512 + h * 64);
#pragma unroll
    for (int d8 = 0; d8 < 8; ++d8) {
      short8 kv = k0p[d8];
#pragma unroll
      for (int j = 0; j < 8; ++j) s += q_s[h * 64 + d8 * 8 + j] * bf2f(kv[j]);
    }
#pragma unroll 8
    for (int f = 0; f < 128; ++f) s += u_s[h][f] * relf_s[lane][f];
    s *= 0.125f;
  }
  // 64-lane softmax
  float m = s;
#pragma unroll
  for (int off = 32; off; off >>= 1) m = fmaxf(m, __shfl_xor(m, off));
  float p = __expf(s - m);
  float sum = p;
#pragma unroll
  for (int off = 32; off; off >>= 1) sum += __shfl_xor(sum, off);
  attn_s[h][lane] = p / sum;

  // w[f] = attn . relf[:,f], f = lane, lane+64   (intra-wave LDS, no barrier)
  {
    float w0 = 0.f, w1 = 0.f;
#pragma unroll 8
    for (int kk = 0; kk < 64; ++kk) {
      float a = attn_s[h][kk];
      w0 += a * relf_s[kk][lane];
      w1 += a * relf_s[kk][lane + 64];
    }
    w_s[h][lane] = w0;
    w_s[h][lane + 64] = w1;
  }

  // out: lane = d
  float o = 0.f;
  {
    const short* v0col = QKV + (size_t)(b * 64) * 1536 + 1024 + h * 64 + lane;
#pragma unroll 16
    for (int kk = 0; kk < 64; ++kk) o += attn_s[h][kk] * bf2f(v0col[(size_t)kk * 1536]);
    const float* wvcol = Wv + 512 * 512 + h * 64 + lane;
#pragma unroll 16
    for (int f = 0; f < 128; ++f) o += w_s[h][f] * wvcol[(size_t)f * 512];
  }
  AO[(size_t)bq * 512 + h * 64 + lane] = f2bf(o);
}

extern "C" void kernel_launch(void* const* d_in, const int* in_sizes, int n_in,
                              void* d_out, int out_size, void* d_ws, size_t ws_size,
                              hipStream_t stream) {
  const float* pe   = (const float*)d_in[0];  // [16,64,512]
  const float* relf = (const float*)d_in[1];  // [16,64,64,128]
  const float* Wq = (const float*)d_in[3];    // [512,512]
  const float* Wk = (const float*)d_in[4];    // [640,512]
  const float* Wv = (const float*)d_in[5];    // [640,512]
  const float* Wo = (const float*)d_in[6];    // [512,512]
  float* out = (float*)d_out;                 // [16,64,512] f32

  short* ws = (short*)d_ws;
  short* pe_bf  = ws;                    // 524288
  short* BtQKV  = pe_bf + 524288;        // 786432
  short* BtO    = BtQKV + 786432;        // 262144
  short* QKVbf  = BtO + 262144;          // 1572864
  short* AObf   = QKVbf + 1572864;       // 524288   (total ~7 MB)

  cast_pe<<<512, 256, 0, stream>>>(pe, pe_bf);
  tcast<<<dim3(64, 16), 256, 0, stream>>>(Wq, Wk, Wv, Wo, BtQKV, BtO);
  gemm_mfma<1><<<dim3(16, 24), 256, 0, stream>>>(pe_bf, BtQKV, nullptr, QKVbf, 512, 1536);
  attn_fused<<<1024, 512, 0, stream>>>(QKVbf, relf, Wk, Wv, AObf);
  gemm_mfma<0><<<dim3(16, 8), 256, 0, stream>>>(AObf, BtO, out, nullptr, 512, 512);
}

// Round 5
// 144.805 us; speedup vs baseline: 1.9061x; 1.3512x over previous
//
#include <hip/hip_runtime.h>
#include <hip/hip_bf16.h>

// B=16, P=64, De=512, F=128, H=8, hs=64, d_model=512.
// Pipeline:
//   prep:      Bt rows = [Wq(0..511)|Wv0(512..1023)|Wk0(1024..1535)] bf16 (transposed),
//              BtO = Wo^T bf16, Wk2t[512][128] = Wk[512:]^T bf16, Wv2bf = Wv[512:] bf16,
//              pe_bf = pe bf16.
//   gemm_qkvu: [1024x1536] = pe_bf @ Bt^T. cols<1024 -> QV (Q|V0) row-major,
//              cols>=1024 (K0) -> K0t2[b][d/2][kk][2] transposed bf16.
//   attn:      per (b,q): u[h,f] = sum_d q[hd]*Wk2t[hd][f];
//              s[kk] = q_h.K0t[:,kk] + relf[kk,:].u_h; softmax;
//              AO = attn.V0 + (attn@relf).Wv2
//   gemm_out:  out = AO @ Wo  (f32 out)
// Workspace: 6.25 MB (hard lesson from R3: 9.4 MB overflowed d_ws and corrupted
// the harness's pristine buffers -> post-timing divergence; stay <= 8 MB).

typedef __attribute__((ext_vector_type(8))) short short8;
typedef __attribute__((ext_vector_type(4))) short short4v;
typedef __attribute__((ext_vector_type(4))) float f32x4;

static __device__ __forceinline__ short f2bf(float x) {
  __hip_bfloat16 h = __float2bfloat16(x);
  union { __hip_bfloat16 h; short s; } u;
  u.h = h;
  return u.s;
}
static __device__ __forceinline__ float bf2f(short s) {
  union { unsigned int u; float f; } c;
  c.u = ((unsigned int)(unsigned short)s) << 16;
  return c.f;
}
static __device__ __forceinline__ float bflo(unsigned int u) {
  union { unsigned int u; float f; } c; c.u = u << 16; return c.f;
}
static __device__ __forceinline__ float bfhi(unsigned int u) {
  union { unsigned int u; float f; } c; c.u = u & 0xFFFF0000u; return c.f;
}

// ---- prep ----
// bid <1024: 32x32 transpose tiles of [Wq|Wv0|Wk0|Wo] -> Bt / BtO
// 1024..1087: Wk2t transpose (Wk[512:640] [128][512] -> [512][128])
// 1088..1151: Wv2bf straight cast (65536 elems)
// 1152..1663: pe cast (524288 elems)
__global__ __launch_bounds__(256) void prep(const float* __restrict__ pe,
                                            const float* __restrict__ Wq,
                                            const float* __restrict__ Wk,
                                            const float* __restrict__ Wv,
                                            const float* __restrict__ Wo,
                                            short* __restrict__ pe_bf,
                                            short* __restrict__ Bt,
                                            short* __restrict__ BtO,
                                            short* __restrict__ Wk2t,
                                            short* __restrict__ Wv2bf) {
  __shared__ float t[32][33];
  const int bid = blockIdx.x, tid = threadIdx.x;
  if (bid < 1024) {
    const int np0 = (bid & 63) * 32, k0 = (bid >> 6) * 32;
    const int tx = tid & 31, ty = tid >> 5;
    const int sid = np0 >> 9;  // 0:Wq 1:Wv0 2:Wk0 3:Wo
    const float* src = (sid == 0) ? Wq : (sid == 1) ? Wv : (sid == 2) ? Wk : Wo;
    const int nc0 = np0 & 511;
#pragma unroll
    for (int r = 0; r < 4; ++r) {
      int kl = ty + r * 8;
      t[kl][tx] = src[(size_t)(k0 + kl) * 512 + nc0 + tx];
    }
    __syncthreads();
#pragma unroll
    for (int r = 0; r < 4; ++r) {
      int nl = ty + r * 8;
      short bv = f2bf(t[tx][nl]);
      int np = np0 + nl;
      if (np < 1536) Bt[(size_t)np * 512 + k0 + tx] = bv;
      else           BtO[(size_t)(np - 1536) * 512 + k0 + tx] = bv;
    }
  } else if (bid < 1088) {
    // Wk2[f][e] (f<128, e<512) -> Wk2t[e][f]
    const int b2 = bid - 1024;
    const int f0 = (b2 & 3) * 32, e0 = (b2 >> 2) * 32;
    const int tx = tid & 31, ty = tid >> 5;
    const float* Wk2 = Wk + 512 * 512;
#pragma unroll
    for (int r = 0; r < 4; ++r) {
      int fl = ty + r * 8;
      t[fl][tx] = Wk2[(size_t)(f0 + fl) * 512 + e0 + tx];
    }
    __syncthreads();
#pragma unroll
    for (int r = 0; r < 4; ++r) {
      int el = ty + r * 8;
      Wk2t[(size_t)(e0 + el) * 128 + f0 + tx] = f2bf(t[tx][el]);
    }
  } else if (bid < 1152) {
    int i = ((bid - 1088) * 256 + tid) * 4;
    const float* Wv2 = Wv + 512 * 512;
    float4 v = *(const float4*)(Wv2 + i);
    short4v o = {f2bf(v.x), f2bf(v.y), f2bf(v.z), f2bf(v.w)};
    *(short4v*)(Wv2bf + i) = o;
  } else {
    int i = ((bid - 1152) * 256 + tid) * 4;
    float4 v = *(const float4*)(pe + i);
    short4v o = {f2bf(v.x), f2bf(v.y), f2bf(v.z), f2bf(v.w)};
    *(short4v*)(pe_bf + i) = o;
  }
}

// ---- big GEMM: [1024 x 1536] = pe_bf @ Bt^T. cols<1024 -> QV; cols>=1024 -> K0t2 transposed.
__global__ __launch_bounds__(256) void gemm_qkvu(const short* __restrict__ A,
                                                 const short* __restrict__ Bt,
                                                 short* __restrict__ QV,
                                                 short* __restrict__ K0t2) {
  const int wave = threadIdx.x >> 6, lane = threadIdx.x & 63;
  const int wr = wave >> 1, wc = wave & 1;
  const int r = lane & 15, g = lane >> 4;
  const int row0 = blockIdx.x * 64 + wr * 32;
  const int col0 = blockIdx.y * 64 + wc * 32;
  const short8* a0p = (const short8*)(A + (size_t)(row0 + r) * 512 + g * 8);
  const short8* a1p = (const short8*)(A + (size_t)(row0 + 16 + r) * 512 + g * 8);
  const short8* b0p = (const short8*)(Bt + (size_t)(col0 + r) * 512 + g * 8);
  const short8* b1p = (const short8*)(Bt + (size_t)(col0 + 16 + r) * 512 + g * 8);
  f32x4 acc00 = {}, acc01 = {}, acc10 = {}, acc11 = {};
#pragma unroll 4
  for (int t = 0; t < 16; ++t) {
    short8 a0 = a0p[t * 4], a1 = a1p[t * 4];
    short8 b0 = b0p[t * 4], b1 = b1p[t * 4];
    acc00 = __builtin_amdgcn_mfma_f32_16x16x32_bf16(a0, b0, acc00, 0, 0, 0);
    acc01 = __builtin_amdgcn_mfma_f32_16x16x32_bf16(a0, b1, acc01, 0, 0, 0);
    acc10 = __builtin_amdgcn_mfma_f32_16x16x32_bf16(a1, b0, acc10, 0, 0, 0);
    acc11 = __builtin_amdgcn_mfma_f32_16x16x32_bf16(a1, b1, acc11, 0, 0, 0);
  }
  const int crow = (lane >> 4) * 4, ccol = lane & 15;
  const bool k0sec = (blockIdx.y >= 16);
#pragma unroll
  for (int i = 0; i < 2; ++i)
#pragma unroll
    for (int j = 0; j < 2; ++j) {
      f32x4 a = (i == 0) ? (j == 0 ? acc00 : acc01) : (j == 0 ? acc10 : acc11);
#pragma unroll
      for (int rg = 0; rg < 4; ++rg) {
        size_t row = row0 + i * 16 + crow + rg;
        size_t col = col0 + j * 16 + ccol;
        short v = f2bf(a[rg]);
        if (!k0sec) {
          QV[row * 1024 + col] = v;
        } else {
          size_t c = col - 1024;           // 0..511
          size_t b = row >> 6, kk = row & 63;
          K0t2[((b * 256 + (c >> 1)) * 64 + kk) * 2 + (c & 1)] = v;
        }
      }
    }
}

// ---- final GEMM: out[1024x512] f32 = AObf @ BtO^T ----
__global__ __launch_bounds__(256) void gemm_out(const short* __restrict__ A,
                                                const short* __restrict__ Bt,
                                                float* __restrict__ C) {
  const int wave = threadIdx.x >> 6, lane = threadIdx.x & 63;
  const int wr = wave >> 1, wc = wave & 1;
  const int r = lane & 15, g = lane >> 4;
  const int row0 = blockIdx.x * 64 + wr * 32;
  const int col0 = blockIdx.y * 64 + wc * 32;
  const short8* a0p = (const short8*)(A + (size_t)(row0 + r) * 512 + g * 8);
  const short8* a1p = (const short8*)(A + (size_t)(row0 + 16 + r) * 512 + g * 8);
  const short8* b0p = (const short8*)(Bt + (size_t)(col0 + r) * 512 + g * 8);
  const short8* b1p = (const short8*)(Bt + (size_t)(col0 + 16 + r) * 512 + g * 8);
  f32x4 acc00 = {}, acc01 = {}, acc10 = {}, acc11 = {};
#pragma unroll 4
  for (int t = 0; t < 16; ++t) {
    short8 a0 = a0p[t * 4], a1 = a1p[t * 4];
    short8 b0 = b0p[t * 4], b1 = b1p[t * 4];
    acc00 = __builtin_amdgcn_mfma_f32_16x16x32_bf16(a0, b0, acc00, 0, 0, 0);
    acc01 = __builtin_amdgcn_mfma_f32_16x16x32_bf16(a0, b1, acc01, 0, 0, 0);
    acc10 = __builtin_amdgcn_mfma_f32_16x16x32_bf16(a1, b0, acc10, 0, 0, 0);
    acc11 = __builtin_amdgcn_mfma_f32_16x16x32_bf16(a1, b1, acc11, 0, 0, 0);
  }
  const int crow = (lane >> 4) * 4, ccol = lane & 15;
#pragma unroll
  for (int i = 0; i < 2; ++i)
#pragma unroll
    for (int j = 0; j < 2; ++j) {
      f32x4 a = (i == 0) ? (j == 0 ? acc00 : acc01) : (j == 0 ? acc10 : acc11);
#pragma unroll
      for (int rg = 0; rg < 4; ++rg)
        C[(size_t)(row0 + i * 16 + crow + rg) * 512 + col0 + j * 16 + ccol] = a[rg];
    }
}

// ---- fused attention: one block per (b,q), 8 waves = 1 head each, all loads coalesced ----
__global__ __launch_bounds__(512) void attn_fused(const short* __restrict__ QV,        // [1024][1024] Q|V0
                                                  const unsigned int* __restrict__ K0t2,  // [16][256][64] uint(2 bf16)
                                                  const float* __restrict__ relf,
                                                  const short* __restrict__ Wk2t,      // [512][128]
                                                  const short* __restrict__ Wv2bf,     // [128][512]
                                                  short* __restrict__ AO) {
  const int bq = blockIdx.x, b = bq >> 6;
  const int tid = threadIdx.x;
  const int h = tid >> 6, lane = tid & 63;

  __shared__ float relf_s[64][129];
  __shared__ float q_s[512];
  __shared__ float u_s[8][128];
  __shared__ float attn_s[8][64];
  __shared__ float w_s[8][128];

  // q: wave h stages its own head's 64 values (intra-wave only consumer)
  q_s[tid] = bf2f(QV[(size_t)bq * 1024 + tid]);

  // relf[b,q]: 64x128 f32, block-cooperative
  const float* rf = relf + (size_t)bq * 8192;
#pragma unroll
  for (int it = 0; it < 4; ++it) {
    int idx = (it * 512 + tid) * 4;
    float4 gv = *(const float4*)(rf + idx);
    int kk = idx >> 7, f = idx & 127;
    relf_s[kk][f + 0] = gv.x; relf_s[kk][f + 1] = gv.y;
    relf_s[kk][f + 2] = gv.z; relf_s[kk][f + 3] = gv.w;
  }
  __syncthreads();  // only block-wide barrier

  // u[h][f] for f = 2*lane, 2*lane+1: coalesced uint rows of Wk2t
  {
    const unsigned int* wp = (const unsigned int*)(Wk2t + (size_t)h * 64 * 128) + lane;
    float u0 = 0.f, u1 = 0.f;
#pragma unroll 8
    for (int d = 0; d < 64; ++d) {
      unsigned int uv = wp[d * 64];
      float qd = q_s[h * 64 + d];
      u0 += qd * bflo(uv);
      u1 += qd * bfhi(uv);
    }
    u_s[h][lane * 2] = u0;
    u_s[h][lane * 2 + 1] = u1;
  }

  // scores: lane = kk
  float s = 0.f;
  {
    const unsigned int* kp = K0t2 + ((size_t)b * 256 + h * 32) * 64 + lane;
#pragma unroll 8
    for (int d2 = 0; d2 < 32; ++d2) {
      unsigned int uv = kp[(size_t)d2 * 64];
      s += q_s[h * 64 + d2 * 2] * bflo(uv) + q_s[h * 64 + d2 * 2 + 1] * bfhi(uv);
    }
#pragma unroll
    for (int f4 = 0; f4 < 32; ++f4) {
      float4 rv = *(const float4*)&relf_s[lane][f4 * 4];
      const float4 uv = *(const float4*)&u_s[h][f4 * 4];
      s += uv.x * rv.x + uv.y * rv.y + uv.z * rv.z + uv.w * rv.w;
    }
    s *= 0.125f;
  }
  // 64-lane softmax
  float m = s;
#pragma unroll
  for (int off = 32; off; off >>= 1) m = fmaxf(m, __shfl_xor(m, off));
  float p = __expf(s - m);
  float sum = p;
#pragma unroll
  for (int off = 32; off; off >>= 1) sum += __shfl_xor(sum, off);
  attn_s[h][lane] = p / sum;

  // w[f] = attn . relf[:,f], f = lane, lane+64 (intra-wave, no barrier)
  {
    float w0 = 0.f, w1 = 0.f;
#pragma unroll 8
    for (int kk = 0; kk < 64; ++kk) {
      float a = attn_s[h][kk];
      w0 += a * relf_s[kk][lane];
      w1 += a * relf_s[kk][lane + 64];
    }
    w_s[h][lane] = w0;
    w_s[h][lane + 64] = w1;
  }

  // out: lane = d
  float o = 0.f;
  {
    const short* v0col = QV + (size_t)(b * 64) * 1024 + 512 + h * 64 + lane;
#pragma unroll 16
    for (int kk = 0; kk < 64; ++kk) o += attn_s[h][kk] * bf2f(v0col[(size_t)kk * 1024]);
    const short* wvcol = Wv2bf + h * 64 + lane;
#pragma unroll 16
    for (int f = 0; f < 128; ++f) o += w_s[h][f] * bf2f(wvcol[(size_t)f * 512]);
  }
  AO[(size_t)bq * 512 + h * 64 + lane] = f2bf(o);
}

extern "C" void kernel_launch(void* const* d_in, const int* in_sizes, int n_in,
                              void* d_out, int out_size, void* d_ws, size_t ws_size,
                              hipStream_t stream) {
  const float* pe   = (const float*)d_in[0];  // [16,64,512]
  const float* relf = (const float*)d_in[1];  // [16,64,64,128]
  const float* Wq = (const float*)d_in[3];    // [512,512]
  const float* Wk = (const float*)d_in[4];    // [640,512]
  const float* Wv = (const float*)d_in[5];    // [640,512]
  const float* Wo = (const float*)d_in[6];    // [512,512]
  float* out = (float*)d_out;                 // [16,64,512] f32

  short* ws = (short*)d_ws;
  short* pe_bf = ws;                    // 524288 shorts (1 MB)
  short* Bt    = pe_bf + 524288;        // 786432 (1.5 MB)
  short* BtO   = Bt + 786432;           // 262144 (0.5 MB)
  short* Wk2t  = BtO + 262144;          // 65536 (128 KB)
  short* Wv2bf = Wk2t + 65536;          // 65536 (128 KB)
  short* QV    = Wv2bf + 65536;         // 1048576 (2 MB)
  short* K0t2  = QV + 1048576;          // 524288 (1 MB)  -> total 6.25 MB
  short* AObf  = pe_bf;                 // alias: pe_bf dead after gemm_qkvu

  prep<<<1664, 256, 0, stream>>>(pe, Wq, Wk, Wv, Wo, pe_bf, Bt, BtO, Wk2t, Wv2bf);
  gemm_qkvu<<<dim3(16, 24), 256, 0, stream>>>(pe_bf, Bt, QV, K0t2);
  attn_fused<<<1024, 512, 0, stream>>>(QV, (const unsigned int*)K0t2, relf, Wk2t, Wv2bf, AObf);
  gemm_out<<<dim3(16, 8), 256, 0, stream>>>(AObf, BtO, out);
}

// Round 7
// 143.049 us; speedup vs baseline: 1.9295x; 1.0123x over previous
//
#include <hip/hip_runtime.h>
#include <hip/hip_bf16.h>

// B=16, P=64, De=512, F=128, H=8, hs=64, d_model=512.
// Pipeline:
//   prep:      Bt rows = [Wq(0..511)|Wv0(512..1023)|Wk0(1024..1535)] bf16 (transposed),
//              BtO = Wo^T bf16, Wk2t[512][128] = Wk[512:]^T bf16, Wv2bf = Wv[512:] bf16,
//              pe_bf = pe bf16.
//   gemm_qkvu: [1024x1536] = pe_bf @ Bt^T. cols<1024 -> QV (Q|V0) row-major,
//              cols>=1024 (K0) -> K0t2[b][d/2][kk][2] transposed bf16.
//   attn:      per (b,q): u[h,f] = sum_d q[hd]*Wk2t[hd][f];
//              s[kk] = q_h.K0t[:,kk] + relf[kk,:].u_h; softmax;
//              AO = attn.V0 + (attn@relf).Wv2
//   gemm_out:  out = AO @ Wo  (f32 out)
// R5 lessons: ws_size = 256 MiB (fills in profile), all kernels < 43 us.
// R6 change: GEMMs get depth-2 super-step register pipelines (16 loads in
// flight ahead of each MFMA burst) to kill the per-K-step L2 latency stalls.

typedef __attribute__((ext_vector_type(8))) short short8;
typedef __attribute__((ext_vector_type(4))) short short4v;
typedef __attribute__((ext_vector_type(4))) float f32x4;

static __device__ __forceinline__ short f2bf(float x) {
  __hip_bfloat16 h = __float2bfloat16(x);
  union { __hip_bfloat16 h; short s; } u;
  u.h = h;
  return u.s;
}
static __device__ __forceinline__ float bf2f(short s) {
  union { unsigned int u; float f; } c;
  c.u = ((unsigned int)(unsigned short)s) << 16;
  return c.f;
}
static __device__ __forceinline__ float bflo(unsigned int u) {
  union { unsigned int u; float f; } c; c.u = u << 16; return c.f;
}
static __device__ __forceinline__ float bfhi(unsigned int u) {
  union { unsigned int u; float f; } c; c.u = u & 0xFFFF0000u; return c.f;
}

// ---- prep ----
// bid <1024: 32x32 transpose tiles of [Wq|Wv0|Wk0|Wo] -> Bt / BtO
// 1024..1087: Wk2t transpose (Wk[512:640] [128][512] -> [512][128])
// 1088..1151: Wv2bf straight cast (65536 elems)
// 1152..1663: pe cast (524288 elems)
__global__ __launch_bounds__(256) void prep(const float* __restrict__ pe,
                                            const float* __restrict__ Wq,
                                            const float* __restrict__ Wk,
                                            const float* __restrict__ Wv,
                                            const float* __restrict__ Wo,
                                            short* __restrict__ pe_bf,
                                            short* __restrict__ Bt,
                                            short* __restrict__ BtO,
                                            short* __restrict__ Wk2t,
                                            short* __restrict__ Wv2bf) {
  __shared__ float t[32][33];
  const int bid = blockIdx.x, tid = threadIdx.x;
  if (bid < 1024) {
    const int np0 = (bid & 63) * 32, k0 = (bid >> 6) * 32;
    const int tx = tid & 31, ty = tid >> 5;
    const int sid = np0 >> 9;  // 0:Wq 1:Wv0 2:Wk0 3:Wo
    const float* src = (sid == 0) ? Wq : (sid == 1) ? Wv : (sid == 2) ? Wk : Wo;
    const int nc0 = np0 & 511;
#pragma unroll
    for (int r = 0; r < 4; ++r) {
      int kl = ty + r * 8;
      t[kl][tx] = src[(size_t)(k0 + kl) * 512 + nc0 + tx];
    }
    __syncthreads();
#pragma unroll
    for (int r = 0; r < 4; ++r) {
      int nl = ty + r * 8;
      short bv = f2bf(t[tx][nl]);
      int np = np0 + nl;
      if (np < 1536) Bt[(size_t)np * 512 + k0 + tx] = bv;
      else           BtO[(size_t)(np - 1536) * 512 + k0 + tx] = bv;
    }
  } else if (bid < 1088) {
    // Wk2[f][e] (f<128, e<512) -> Wk2t[e][f]
    const int b2 = bid - 1024;
    const int f0 = (b2 & 3) * 32, e0 = (b2 >> 2) * 32;
    const int tx = tid & 31, ty = tid >> 5;
    const float* Wk2 = Wk + 512 * 512;
#pragma unroll
    for (int r = 0; r < 4; ++r) {
      int fl = ty + r * 8;
      t[fl][tx] = Wk2[(size_t)(f0 + fl) * 512 + e0 + tx];
    }
    __syncthreads();
#pragma unroll
    for (int r = 0; r < 4; ++r) {
      int el = ty + r * 8;
      Wk2t[(size_t)(e0 + el) * 128 + f0 + tx] = f2bf(t[tx][el]);
    }
  } else if (bid < 1152) {
    int i = ((bid - 1088) * 256 + tid) * 4;
    const float* Wv2 = Wv + 512 * 512;
    float4 v = *(const float4*)(Wv2 + i);
    short4v o = {f2bf(v.x), f2bf(v.y), f2bf(v.z), f2bf(v.w)};
    *(short4v*)(Wv2bf + i) = o;
  } else {
    int i = ((bid - 1152) * 256 + tid) * 4;
    float4 v = *(const float4*)(pe + i);
    short4v o = {f2bf(v.x), f2bf(v.y), f2bf(v.z), f2bf(v.w)};
    *(short4v*)(pe_bf + i) = o;
  }
}

// ---- big GEMM: [1024 x 1536] = pe_bf @ Bt^T. cols<1024 -> QV; cols>=1024 -> K0t2 transposed.
// Depth-2 super-step register pipeline: each super-step = 4 K-chunks (128 K),
// 16 fragment loads issued a full super-step ahead of the MFMAs consuming them.
__global__ __launch_bounds__(256) void gemm_qkvu(const short* __restrict__ A,
                                                 const short* __restrict__ Bt,
                                                 short* __restrict__ QV,
                                                 short* __restrict__ K0t2) {
  const int wave = threadIdx.x >> 6, lane = threadIdx.x & 63;
  const int wr = wave >> 1, wc = wave & 1;
  const int r = lane & 15, g = lane >> 4;
  const int row0 = blockIdx.x * 64 + wr * 32;
  const int col0 = blockIdx.y * 64 + wc * 32;
  const short8* a0p = (const short8*)(A + (size_t)(row0 + r) * 512 + g * 8);
  const short8* a1p = (const short8*)(A + (size_t)(row0 + 16 + r) * 512 + g * 8);
  const short8* b0p = (const short8*)(Bt + (size_t)(col0 + r) * 512 + g * 8);
  const short8* b1p = (const short8*)(Bt + (size_t)(col0 + 16 + r) * 512 + g * 8);
  f32x4 acc00 = {}, acc01 = {}, acc10 = {}, acc11 = {};
  short8 A0[2][4], A1[2][4], B0[2][4], B1[2][4];
  auto LOAD = [&](int buf, int ss) {
#pragma unroll
    for (int c = 0; c < 4; ++c) {
      A0[buf][c] = a0p[(ss * 4 + c) * 4];
      A1[buf][c] = a1p[(ss * 4 + c) * 4];
      B0[buf][c] = b0p[(ss * 4 + c) * 4];
      B1[buf][c] = b1p[(ss * 4 + c) * 4];
    }
  };
  auto MM = [&](int buf) {
#pragma unroll
    for (int c = 0; c < 4; ++c) {
      acc00 = __builtin_amdgcn_mfma_f32_16x16x32_bf16(A0[buf][c], B0[buf][c], acc00, 0, 0, 0);
      acc01 = __builtin_amdgcn_mfma_f32_16x16x32_bf16(A0[buf][c], B1[buf][c], acc01, 0, 0, 0);
      acc10 = __builtin_amdgcn_mfma_f32_16x16x32_bf16(A1[buf][c], B0[buf][c], acc10, 0, 0, 0);
      acc11 = __builtin_amdgcn_mfma_f32_16x16x32_bf16(A1[buf][c], B1[buf][c], acc11, 0, 0, 0);
    }
  };
  LOAD(0, 0);
  LOAD(1, 1);
  MM(0);
  LOAD(0, 2);
  MM(1);
  LOAD(1, 3);
  MM(0);
  MM(1);
  const int crow = (lane >> 4) * 4, ccol = lane & 15;
  const bool k0sec = (blockIdx.y >= 16);
#pragma unroll
  for (int i = 0; i < 2; ++i)
#pragma unroll
    for (int j = 0; j < 2; ++j) {
      f32x4 a = (i == 0) ? (j == 0 ? acc00 : acc01) : (j == 0 ? acc10 : acc11);
#pragma unroll
      for (int rg = 0; rg < 4; ++rg) {
        size_t row = row0 + i * 16 + crow + rg;
        size_t col = col0 + j * 16 + ccol;
        short v = f2bf(a[rg]);
        if (!k0sec) {
          QV[row * 1024 + col] = v;
        } else {
          size_t c = col - 1024;           // 0..511
          size_t b = row >> 6, kk = row & 63;
          K0t2[((b * 256 + (c >> 1)) * 64 + kk) * 2 + (c & 1)] = v;
        }
      }
    }
}

// ---- final GEMM: out[1024x512] f32 = AObf @ BtO^T, same pipeline ----
__global__ __launch_bounds__(256) void gemm_out(const short* __restrict__ A,
                                                const short* __restrict__ Bt,
                                                float* __restrict__ C) {
  const int wave = threadIdx.x >> 6, lane = threadIdx.x & 63;
  const int wr = wave >> 1, wc = wave & 1;
  const int r = lane & 15, g = lane >> 4;
  const int row0 = blockIdx.x * 64 + wr * 32;
  const int col0 = blockIdx.y * 64 + wc * 32;
  const short8* a0p = (const short8*)(A + (size_t)(row0 + r) * 512 + g * 8);
  const short8* a1p = (const short8*)(A + (size_t)(row0 + 16 + r) * 512 + g * 8);
  const short8* b0p = (const short8*)(Bt + (size_t)(col0 + r) * 512 + g * 8);
  const short8* b1p = (const short8*)(Bt + (size_t)(col0 + 16 + r) * 512 + g * 8);
  f32x4 acc00 = {}, acc01 = {}, acc10 = {}, acc11 = {};
  short8 A0[2][4], A1[2][4], B0[2][4], B1[2][4];
  auto LOAD = [&](int buf, int ss) {
#pragma unroll
    for (int c = 0; c < 4; ++c) {
      A0[buf][c] = a0p[(ss * 4 + c) * 4];
      A1[buf][c] = a1p[(ss * 4 + c) * 4];
      B0[buf][c] = b0p[(ss * 4 + c) * 4];
      B1[buf][c] = b1p[(ss * 4 + c) * 4];
    }
  };
  auto MM = [&](int buf) {
#pragma unroll
    for (int c = 0; c < 4; ++c) {
      acc00 = __builtin_amdgcn_mfma_f32_16x16x32_bf16(A0[buf][c], B0[buf][c], acc00, 0, 0, 0);
      acc01 = __builtin_amdgcn_mfma_f32_16x16x32_bf16(A0[buf][c], B1[buf][c], acc01, 0, 0, 0);
      acc10 = __builtin_amdgcn_mfma_f32_16x16x32_bf16(A1[buf][c], B0[buf][c], acc10, 0, 0, 0);
      acc11 = __builtin_amdgcn_mfma_f32_16x16x32_bf16(A1[buf][c], B1[buf][c], acc11, 0, 0, 0);
    }
  };
  LOAD(0, 0);
  LOAD(1, 1);
  MM(0);
  LOAD(0, 2);
  MM(1);
  LOAD(1, 3);
  MM(0);
  MM(1);
  const int crow = (lane >> 4) * 4, ccol = lane & 15;
#pragma unroll
  for (int i = 0; i < 2; ++i)
#pragma unroll
    for (int j = 0; j < 2; ++j) {
      f32x4 a = (i == 0) ? (j == 0 ? acc00 : acc01) : (j == 0 ? acc10 : acc11);
#pragma unroll
      for (int rg = 0; rg < 4; ++rg)
        C[(size_t)(row0 + i * 16 + crow + rg) * 512 + col0 + j * 16 + ccol] = a[rg];
    }
}

// ---- fused attention: one block per (b,q), 8 waves = 1 head each, all loads coalesced ----
__global__ __launch_bounds__(512) void attn_fused(const short* __restrict__ QV,        // [1024][1024] Q|V0
                                                  const unsigned int* __restrict__ K0t2,  // [16][256][64] uint(2 bf16)
                                                  const float* __restrict__ relf,
                                                  const short* __restrict__ Wk2t,      // [512][128]
                                                  const short* __restrict__ Wv2bf,     // [128][512]
                                                  short* __restrict__ AO) {
  const int bq = blockIdx.x, b = bq >> 6;
  const int tid = threadIdx.x;
  const int h = tid >> 6, lane = tid & 63;

  __shared__ float relf_s[64][129];
  __shared__ float q_s[512];
  __shared__ float u_s[8][128];
  __shared__ float attn_s[8][64];
  __shared__ float w_s[8][128];

  // q: wave h stages its own head's 64 values (intra-wave only consumer)
  q_s[tid] = bf2f(QV[(size_t)bq * 1024 + tid]);

  // relf[b,q]: 64x128 f32, block-cooperative
  const float* rf = relf + (size_t)bq * 8192;
#pragma unroll
  for (int it = 0; it < 4; ++it) {
    int idx = (it * 512 + tid) * 4;
    float4 gv = *(const float4*)(rf + idx);
    int kk = idx >> 7, f = idx & 127;
    relf_s[kk][f + 0] = gv.x; relf_s[kk][f + 1] = gv.y;
    relf_s[kk][f + 2] = gv.z; relf_s[kk][f + 3] = gv.w;
  }
  __syncthreads();  // only block-wide barrier

  // u[h][f] for f = 2*lane, 2*lane+1: coalesced uint rows of Wk2t
  {
    const unsigned int* wp = (const unsigned int*)(Wk2t + (size_t)h * 64 * 128) + lane;
    float u0 = 0.f, u1 = 0.f;
#pragma unroll 8
    for (int d = 0; d < 64; ++d) {
      unsigned int uv = wp[d * 64];
      float qd = q_s[h * 64 + d];
      u0 += qd * bflo(uv);
      u1 += qd * bfhi(uv);
    }
    u_s[h][lane * 2] = u0;
    u_s[h][lane * 2 + 1] = u1;
  }

  // scores: lane = kk
  float s = 0.f;
  {
    const unsigned int* kp = K0t2 + ((size_t)b * 256 + h * 32) * 64 + lane;
#pragma unroll 8
    for (int d2 = 0; d2 < 32; ++d2) {
      unsigned int uv = kp[(size_t)d2 * 64];
      s += q_s[h * 64 + d2 * 2] * bflo(uv) + q_s[h * 64 + d2 * 2 + 1] * bfhi(uv);
    }
#pragma unroll
    for (int f4 = 0; f4 < 32; ++f4) {
      float4 rv = *(const float4*)&relf_s[lane][f4 * 4];
      const float4 uv = *(const float4*)&u_s[h][f4 * 4];
      s += uv.x * rv.x + uv.y * rv.y + uv.z * rv.z + uv.w * rv.w;
    }
    s *= 0.125f;
  }
  // 64-lane softmax
  float m = s;
#pragma unroll
  for (int off = 32; off; off >>= 1) m = fmaxf(m, __shfl_xor(m, off));
  float p = __expf(s - m);
  float sum = p;
#pragma unroll
  for (int off = 32; off; off >>= 1) sum += __shfl_xor(sum, off);
  attn_s[h][lane] = p / sum;

  // w[f] = attn . relf[:,f], f = lane, lane+64 (intra-wave, no barrier)
  {
    float w0 = 0.f, w1 = 0.f;
#pragma unroll 8
    for (int kk = 0; kk < 64; ++kk) {
      float a = attn_s[h][kk];
      w0 += a * relf_s[kk][lane];
      w1 += a * relf_s[kk][lane + 64];
    }
    w_s[h][lane] = w0;
    w_s[h][lane + 64] = w1;
  }

  // out: lane = d
  float o = 0.f;
  {
    const short* v0col = QV + (size_t)(b * 64) * 1024 + 512 + h * 64 + lane;
#pragma unroll 16
    for (int kk = 0; kk < 64; ++kk) o += attn_s[h][kk] * bf2f(v0col[(size_t)kk * 1024]);
    const short* wvcol = Wv2bf + h * 64 + lane;
#pragma unroll 16
    for (int f = 0; f < 128; ++f) o += w_s[h][f] * bf2f(wvcol[(size_t)f * 512]);
  }
  AO[(size_t)bq * 512 + h * 64 + lane] = f2bf(o);
}

extern "C" void kernel_launch(void* const* d_in, const int* in_sizes, int n_in,
                              void* d_out, int out_size, void* d_ws, size_t ws_size,
                              hipStream_t stream) {
  const float* pe   = (const float*)d_in[0];  // [16,64,512]
  const float* relf = (const float*)d_in[1];  // [16,64,64,128]
  const float* Wq = (const float*)d_in[3];    // [512,512]
  const float* Wk = (const float*)d_in[4];    // [640,512]
  const float* Wv = (const float*)d_in[5];    // [640,512]
  const float* Wo = (const float*)d_in[6];    // [512,512]
  float* out = (float*)d_out;                 // [16,64,512] f32

  short* ws = (short*)d_ws;
  short* pe_bf = ws;                    // 524288 shorts (1 MB)
  short* Bt    = pe_bf + 524288;        // 786432 (1.5 MB)
  short* BtO   = Bt + 786432;           // 262144 (0.5 MB)
  short* Wk2t  = BtO + 262144;          // 65536 (128 KB)
  short* Wv2bf = Wk2t + 65536;          // 65536 (128 KB)
  short* QV    = Wv2bf + 65536;         // 1048576 (2 MB)
  short* K0t2  = QV + 1048576;          // 524288 (1 MB)
  short* AObf  = pe_bf;                 // alias: pe_bf dead after gemm_qkvu

  prep<<<1664, 256, 0, stream>>>(pe, Wq, Wk, Wv, Wo, pe_bf, Bt, BtO, Wk2t, Wv2bf);
  gemm_qkvu<<<dim3(16, 24), 256, 0, stream>>>(pe_bf, Bt, QV, K0t2);
  attn_fused<<<1024, 512, 0, stream>>>(QV, (const unsigned int*)K0t2, relf, Wk2t, Wv2bf, AObf);
  gemm_out<<<dim3(16, 8), 256, 0, stream>>>(AObf, BtO, out);
}